// Round 18
// baseline (24.538 us; speedup 1.0000x reference)
//
#include <hip/hip_runtime.h>
#include <hip/hip_bf16.h>

// Problem: B=8, CIN=8, COUT=8, NX=NT=512, M1=M2=4.
// out[b,o,z,i] = Re( sum_{m,kw} c2[b,o,m,kw] e^{2pi i (m z + kw i)/512} ) / 65536
// R18: producer/consumer pipeline. 2048 co-resident blocks (8/CU):
//   blocks 0..511   = producers: 2 dft tasks each (task p, then p+512) so
//                     batches b=0..3 finish in round 1 -> early consumer wake.
//   blocks 512..2047 = consumers: spin done[b]>=128 (s_sleep), mix from Yg
//                     (agent atomics), eval chunk, NT stores. Blocks 512..1023
//                     take a 2nd eval task (b=6,7).
// Rationale: R16/R17 located both kernels at structural rooflines
// (even-row fetch = half HBM channels ~3.15 TB/s -> 10us; write 64MB -> 10us);
// only overlap of read/write phases can beat 24.4.
// Ledger: NT stores +4us (R11); HW sincos +1.2 (R17); fused-lockstep neutral
// (R14/R15); grid.sync ~100us (R5). Fallback: proven R13/R17 pair.

#define PI2 6.283185307179586f

typedef float vfloat4 __attribute__((ext_vector_type(4)));

__device__ __forceinline__ void fsincos(float r, float* s, float* c) {
    r = r - floorf(r);
    *s = __builtin_amdgcn_sinf(r);
    *c = __builtin_amdgcn_cosf(r);
}

__device__ __forceinline__ float foldred(float u, float v, int msk, int lane) {
    float send = (lane & msk) ? u : v;
    float recv = __shfl_xor(send, msk, 64);
    return ((lane & msk) ? v : u) + recv;
}

__device__ __forceinline__ float fold8(const float* ar, const float* ai, int lane) {
    float A0 = foldred(ar[0], ai[0], 1, lane);
    float A1 = foldred(ar[1], ai[1], 1, lane);
    float A2 = foldred(ar[2], ai[2], 1, lane);
    float A3 = foldred(ar[3], ai[3], 1, lane);
    float B0 = foldred(A0, A1, 2, lane);
    float B1 = foldred(A2, A3, 2, lane);
    float C  = foldred(B0, B1, 4, lane);
    C += __shfl_xor(C, 8, 64);
    C += __shfl_xor(C, 16, 64);
    C += __shfl_xor(C, 32, 64);
    return C;
}

// ---- producer task body: dft for (bc,g), 4 waves x 4 rows, Yg atomic stores ----
__device__ __forceinline__ void dft_task(const float* __restrict__ x,
                                         float* __restrict__ Yg,
                                         float vals[4][64],
                                         int task, int lane, int w) {
    int bc = task >> 4;           // b*8+ci
    int g  = task & 15;
    int y0 = g * 16 + w * 4;

    const float* base = x + (size_t)bc * 512 * 512;
    vfloat4 A0[4], A1[4];
#pragma unroll
    for (int r = 0; r < 4; ++r) {
        const vfloat4* row = (const vfloat4*)(base + (size_t)(2 * (y0 + r)) * 512);
        A0[r] = __builtin_nontemporal_load(&row[lane]);
        A1[r] = __builtin_nontemporal_load(&row[lane + 64]);
    }

    float s, c;
    fsincos((float)lane * 0.0078125f, &s, &c);      // lane/128
    float er[4], ei[4], orE[4], oiE[4];
    er[0] = 1.f; ei[0] = 0.f;
    er[1] = c;   ei[1] = -s;
    er[2] = er[1]*er[1] - ei[1]*ei[1];  ei[2] = 2.f*er[1]*ei[1];
    er[3] = er[2]*er[1] - ei[2]*ei[1];  ei[3] = er[2]*ei[1] + ei[2]*er[1];
    const float rr1 = 0.999698818696204f, ri1 = -0.024541228522912f;
    const float rr2 = 0.998795456205172f, ri2 = -0.049067674327418f;
    const float rr3 = 0.997290456678690f, ri3 = -0.073564563599667f;
    orE[0] = 1.f; oiE[0] = 0.f;
    orE[1] = er[1]*rr1 - ei[1]*ri1;  oiE[1] = er[1]*ri1 + ei[1]*rr1;
    orE[2] = er[2]*rr2 - ei[2]*ri2;  oiE[2] = er[2]*ri2 + ei[2]*rr2;
    orE[3] = er[3]*rr3 - ei[3]*ri3;  oiE[3] = er[3]*ri3 + ei[3]*rr3;

    int midx = lane >> 3;
    float mf = (midx < 4) ? (float)midx : (float)(midx - 8);
    float snm, csm;
    fsincos(mf * (float)y0 * 0.00390625f, &snm, &csm);
    float cs = csm, ty = -snm;
    float smm, cmm;
    fsincos(mf * 0.00390625f, &smm, &cmm);

    float acc = 0.f;
#pragma unroll
    for (int r = 0; r < 4; ++r) {
        float s0 = A0[r][0] + A1[r][0], d0 = A0[r][0] - A1[r][0];
        float s2 = A0[r][2] + A1[r][2], d2 = A0[r][2] - A1[r][2];
        float ar[4], ai[4];
#pragma unroll
        for (int kw = 0; kw < 4; ++kw) {
            float E = (kw & 1) ? d0 : s0;
            float O = (kw & 1) ? d2 : s2;
            ar[kw] = E * er[kw] + O * orE[kw];
            ai[kw] = E * ei[kw] + O * oiE[kw];
        }
        float C  = fold8(ar, ai, lane);
        float pt = __shfl_xor(C, 1, 64);
        float sel = (lane & 1) ? ty : -ty;
        acc += C * cs + pt * sel;
        float nc = cs * cmm + ty * smm;
        float nt = ty * cmm - cs * smm;
        cs = nc; ty = nt;
    }
    vals[w][lane] = acc;
    __syncthreads();

    if (w == 0) {
        int b = bc >> 3, ci = bc & 7;
        float sum = vals[0][lane] + vals[1][lane] + vals[2][lane] + vals[3][lane];
        __hip_atomic_store(&Yg[((size_t)((b * 16 + g) * 8 + ci)) * 64 + lane], sum,
                           __ATOMIC_RELEASE, __HIP_MEMORY_SCOPE_AGENT);
    }
    __syncthreads();   // drains vmcnt -> stores visible before signal
}

// ---------------- pipelined kernel ----------------
__global__ __launch_bounds__(256, 8) void k_pipe(const float* __restrict__ x,
                                                 const float* __restrict__ w1,
                                                 const float* __restrict__ w2,
                                                 float* __restrict__ Yg,
                                                 unsigned int* __restrict__ done,
                                                 float* __restrict__ out) {
    __shared__ float vals[4][64];
    __shared__ float lcf[64];

    int lane = threadIdx.x & 63;
    int w    = threadIdx.x >> 6;
    int blk  = blockIdx.x;

    if (blk < 512) {
        // ================= producer =================
#pragma unroll
        for (int rnd = 0; rnd < 2; ++rnd) {
            int task = blk + rnd * 512;          // round 0: b=0..3, round 1: b=4..7
            dft_task(x, Yg, vals, task, lane, w);
            if (threadIdx.x == 0) {
                int b = task >> 7;
                __hip_atomic_fetch_add(&done[b], 1u, __ATOMIC_RELEASE,
                                       __HIP_MEMORY_SCOPE_AGENT);
            }
        }
        return;
    }

    // ================= consumer =================
    int cb = blk - 512;
    int ntask = (cb < 512) ? 2 : 1;

    float c1b, s1b;
    fsincos((float)lane * 0.0078125f, &s1b, &c1b);
    const float cr = 0.99992470183839f;
    const float sr = 0.012271538285720f;
    const float inv = 1.0f / 65536.0f;

    for (int q = 0; q < ntask; ++q) {
        int e = cb + q * 1536;                   // eval task [0,2048)
        int bo = e >> 5, chunk = e & 31;
        int b = bo >> 3, o = bo & 7;

        if (threadIdx.x == 0) {
            while (__hip_atomic_load(&done[b], __ATOMIC_ACQUIRE,
                                     __HIP_MEMORY_SCOPE_AGENT) < 128u)
                __builtin_amdgcn_s_sleep(2);
        }
        __syncthreads();

        // ---- mix: c2 for this bo from Yg ----
        {
            int midx = lane >> 3, kw = (lane >> 1) & 3, ri = lane & 1, mx = midx & 3;
            const float* wt = (midx < 4) ? w1 : w2;
            float wr_[8], swi_[8];
#pragma unroll
            for (int ci = 0; ci < 8; ++ci) {
                const float* wp = wt + ((((ci * 8 + o) * 4 + mx) * 4 + kw) * 2);
                wr_[ci]  = wp[0];
                swi_[ci] = ri ? wp[1] : -wp[1];
            }
            float acc = 0.f;
#pragma unroll
            for (int gi = 0; gi < 4; ++gi) {
                int g = w + gi * 4;
                float* Yp = Yg + ((size_t)((b * 16 + g) * 8)) * 64 + lane;
#pragma unroll
                for (int ci = 0; ci < 8; ++ci) {
                    float Yv = __hip_atomic_load(Yp + ci * 64, __ATOMIC_RELAXED,
                                                 __HIP_MEMORY_SCOPE_AGENT);
                    float pt = __shfl_xor(Yv, 1, 64);
                    acc += Yv * wr_[ci] + pt * swi_[ci];
                }
            }
            vals[w][lane] = acc;
        }
        __syncthreads();
        if (w == 0)
            lcf[lane] = vals[0][lane] + vals[1][lane] + vals[2][lane] + vals[3][lane];
        __syncthreads();

        // ---- eval: 2 z per wave, rows z and z+256 ----
        int ll = lane & 31;
        int kw = ll & 3, midx = (ll >> 2) & 7;
        float m = (midx < 4) ? (float)midx : (float)(midx - 8);
        float2 cc = make_float2(lcf[(midx * 4 + kw) * 2], lcf[(midx * 4 + kw) * 2 + 1]);
        float sgm = (midx & 1) ? -1.f : 1.f;

#pragma unroll
        for (int ez = 0; ez < 2; ++ez) {
            int z = chunk * 8 + w * 2 + ez;

            float s, c;
            fsincos(m * (float)z * 0.001953125f, &s, &c);
            float hx = cc.x * c - cc.y * s;
            float hy = cc.x * s + cc.y * c;
            float gx = sgm * hx, gy = sgm * hy;

            float F = foldred(hx, hy, 4, lane);
            F += __shfl_xor(F, 8, 64);
            F += __shfl_xor(F, 16, 64);
            float G = foldred(gx, gy, 4, lane);
            G += __shfl_xor(G, 8, 64);
            G += __shfl_xor(G, 16, 64);
            float h0x = __shfl(F, 0, 64);
            float h1x = __shfl(F, 1, 64), h2x = __shfl(F, 2, 64), h3x = __shfl(F, 3, 64);
            float h1y = __shfl(F, 5, 64), h2y = __shfl(F, 6, 64), h3y = __shfl(F, 7, 64);
            float g0x = __shfl(G, 0, 64);
            float g1x = __shfl(G, 1, 64), g2x = __shfl(G, 2, 64), g3x = __shfl(G, 3, 64);
            float g1y = __shfl(G, 5, 64), g2y = __shfl(G, 6, 64), g3y = __shfl(G, 7, 64);

            float* orow0 = out + (size_t)(bo * 512 + z) * 512;
            float* orow1 = orow0 + 256 * 512;

            float c1 = c1b, s1 = s1b;
            vfloat4 r0, r1, q0, q1;
#pragma unroll
            for (int j = 0; j < 4; ++j) {
                float c2a = c1 * c1 - s1 * s1, s2a = 2.f * c1 * s1;
                float c3a = c2a * c1 - s2a * s1, s3a = s2a * c1 + c2a * s1;
                float t1 = h1x * c1  - h1y * s1;
                float t2 = h2x * c2a - h2y * s2a;
                float t3 = h3x * c3a - h3y * s3a;
                r0[j] = (h0x + t1 + t2 + t3) * inv;
                r1[j] = (h0x - t1 + t2 - t3) * inv;
                float u1 = g1x * c1  - g1y * s1;
                float u2 = g2x * c2a - g2y * s2a;
                float u3 = g3x * c3a - g3y * s3a;
                q0[j] = (g0x + u1 + u2 + u3) * inv;
                q1[j] = (g0x - u1 + u2 - u3) * inv;
                float nc = c1 * cr - s1 * sr;
                float ns = s1 * cr + c1 * sr;
                c1 = nc; s1 = ns;
            }
            __builtin_nontemporal_store(r0, (vfloat4*)(orow0 + lane * 4));
            __builtin_nontemporal_store(r1, (vfloat4*)(orow0 + 256 + lane * 4));
            __builtin_nontemporal_store(q0, (vfloat4*)(orow1 + lane * 4));
            __builtin_nontemporal_store(q1, (vfloat4*)(orow1 + 256 + lane * 4));
        }
        __syncthreads();    // vals/lcf reuse safety for next task
    }
}

// ---------------- fallback: proven R17 two-kernel path ----------------
__global__ __launch_bounds__(256) void k_dft_t(const float* __restrict__ x,
                                               float* __restrict__ Yg) {
    __shared__ float vals[4][64];
    int lane = threadIdx.x & 63;
    int w    = threadIdx.x >> 6;
    int task = blockIdx.x;
    int bc = task >> 4, g = task & 15;
    int y0 = g * 16 + w * 4;

    const float* base = x + (size_t)bc * 512 * 512;
    vfloat4 A0[4], A1[4];
#pragma unroll
    for (int r = 0; r < 4; ++r) {
        const vfloat4* row = (const vfloat4*)(base + (size_t)(2 * (y0 + r)) * 512);
        A0[r] = __builtin_nontemporal_load(&row[lane]);
        A1[r] = __builtin_nontemporal_load(&row[lane + 64]);
    }
    float s, c;
    fsincos((float)lane * 0.0078125f, &s, &c);
    float er[4], ei[4], orE[4], oiE[4];
    er[0] = 1.f; ei[0] = 0.f;
    er[1] = c;   ei[1] = -s;
    er[2] = er[1]*er[1] - ei[1]*ei[1];  ei[2] = 2.f*er[1]*ei[1];
    er[3] = er[2]*er[1] - ei[2]*ei[1];  ei[3] = er[2]*ei[1] + ei[2]*er[1];
    const float rr1 = 0.999698818696204f, ri1 = -0.024541228522912f;
    const float rr2 = 0.998795456205172f, ri2 = -0.049067674327418f;
    const float rr3 = 0.997290456678690f, ri3 = -0.073564563599667f;
    orE[0] = 1.f; oiE[0] = 0.f;
    orE[1] = er[1]*rr1 - ei[1]*ri1;  oiE[1] = er[1]*ri1 + ei[1]*rr1;
    orE[2] = er[2]*rr2 - ei[2]*ri2;  oiE[2] = er[2]*ri2 + ei[2]*rr2;
    orE[3] = er[3]*rr3 - ei[3]*ri3;  oiE[3] = er[3]*ri3 + ei[3]*rr3;

    int midx = lane >> 3;
    float mf = (midx < 4) ? (float)midx : (float)(midx - 8);
    float snm, csm;
    fsincos(mf * (float)y0 * 0.00390625f, &snm, &csm);
    float cs = csm, ty = -snm;
    float smm, cmm;
    fsincos(mf * 0.00390625f, &smm, &cmm);

    float acc = 0.f;
#pragma unroll
    for (int r = 0; r < 4; ++r) {
        float s0 = A0[r][0] + A1[r][0], d0 = A0[r][0] - A1[r][0];
        float s2 = A0[r][2] + A1[r][2], d2 = A0[r][2] - A1[r][2];
        float ar[4], ai[4];
#pragma unroll
        for (int kw = 0; kw < 4; ++kw) {
            float E = (kw & 1) ? d0 : s0;
            float O = (kw & 1) ? d2 : s2;
            ar[kw] = E * er[kw] + O * orE[kw];
            ai[kw] = E * ei[kw] + O * oiE[kw];
        }
        float C  = fold8(ar, ai, lane);
        float pt = __shfl_xor(C, 1, 64);
        float sel = (lane & 1) ? ty : -ty;
        acc += C * cs + pt * sel;
        float nc = cs * cmm + ty * smm;
        float nt = ty * cmm - cs * smm;
        cs = nc; ty = nt;
    }
    vals[w][lane] = acc;
    __syncthreads();
    if (threadIdx.x < 64) {
        int b = bc >> 3, ci = bc & 7;
        float sum = vals[0][lane] + vals[1][lane] + vals[2][lane] + vals[3][lane];
        Yg[((size_t)((b * 16 + g) * 8 + ci)) * 64 + lane] = sum;
    }
}

__global__ __launch_bounds__(256) void k_mix_eval(const float* __restrict__ Yg,
                                                  const float* __restrict__ w1,
                                                  const float* __restrict__ w2,
                                                  float* __restrict__ out) {
    __shared__ float vals[4][64];
    __shared__ float lcf[64];
    int lane  = threadIdx.x & 63;
    int w     = threadIdx.x >> 6;
    int bo    = blockIdx.x >> 5;
    int chunk = blockIdx.x & 31;
    int b = bo >> 3, o = bo & 7;
    {
        int midx = lane >> 3, kw = (lane >> 1) & 3, ri = lane & 1, mx = midx & 3;
        const float* wt = (midx < 4) ? w1 : w2;
        float wr_[8], swi_[8];
#pragma unroll
        for (int ci = 0; ci < 8; ++ci) {
            const float* wp = wt + ((((ci * 8 + o) * 4 + mx) * 4 + kw) * 2);
            wr_[ci]  = wp[0];
            swi_[ci] = ri ? wp[1] : -wp[1];
        }
        float acc = 0.f;
#pragma unroll
        for (int gi = 0; gi < 4; ++gi) {
            int g = w + gi * 4;
            const float* Yp = Yg + ((size_t)((b * 16 + g) * 8)) * 64 + lane;
#pragma unroll
            for (int ci = 0; ci < 8; ++ci) {
                float Yv = Yp[ci * 64];
                float pt = __shfl_xor(Yv, 1, 64);
                acc += Yv * wr_[ci] + pt * swi_[ci];
            }
        }
        vals[w][lane] = acc;
    }
    __syncthreads();
    if (w == 0)
        lcf[lane] = vals[0][lane] + vals[1][lane] + vals[2][lane] + vals[3][lane];
    __syncthreads();

    float c1b, s1b;
    fsincos((float)lane * 0.0078125f, &s1b, &c1b);
    const float cr = 0.99992470183839f;
    const float sr = 0.012271538285720f;
    const float inv = 1.0f / 65536.0f;
    int ll = lane & 31;
    int kw = ll & 3, midx = (ll >> 2) & 7;
    float m = (midx < 4) ? (float)midx : (float)(midx - 8);
    float2 cc = make_float2(lcf[ll * 2], lcf[ll * 2 + 1]);
    float sgm = (midx & 1) ? -1.f : 1.f;
#pragma unroll
    for (int e = 0; e < 2; ++e) {
        int z = chunk * 8 + w * 2 + e;
        float s, c;
        fsincos(m * (float)z * 0.001953125f, &s, &c);
        float hx = cc.x * c - cc.y * s;
        float hy = cc.x * s + cc.y * c;
        float gx = sgm * hx, gy = sgm * hy;
        float F = foldred(hx, hy, 4, lane);
        F += __shfl_xor(F, 8, 64);
        F += __shfl_xor(F, 16, 64);
        float G = foldred(gx, gy, 4, lane);
        G += __shfl_xor(G, 8, 64);
        G += __shfl_xor(G, 16, 64);
        float h0x = __shfl(F, 0, 64);
        float h1x = __shfl(F, 1, 64), h2x = __shfl(F, 2, 64), h3x = __shfl(F, 3, 64);
        float h1y = __shfl(F, 5, 64), h2y = __shfl(F, 6, 64), h3y = __shfl(F, 7, 64);
        float g0x = __shfl(G, 0, 64);
        float g1x = __shfl(G, 1, 64), g2x = __shfl(G, 2, 64), g3x = __shfl(G, 3, 64);
        float g1y = __shfl(G, 5, 64), g2y = __shfl(G, 6, 64), g3y = __shfl(G, 7, 64);
        float* orow0 = out + (size_t)(bo * 512 + z) * 512;
        float* orow1 = orow0 + 256 * 512;
        float c1 = c1b, s1 = s1b;
        vfloat4 r0, r1, q0, q1;
#pragma unroll
        for (int j = 0; j < 4; ++j) {
            float c2a = c1 * c1 - s1 * s1, s2a = 2.f * c1 * s1;
            float c3a = c2a * c1 - s2a * s1, s3a = s2a * c1 + c2a * s1;
            float t1 = h1x * c1  - h1y * s1;
            float t2 = h2x * c2a - h2y * s2a;
            float t3 = h3x * c3a - h3y * s3a;
            r0[j] = (h0x + t1 + t2 + t3) * inv;
            r1[j] = (h0x - t1 + t2 - t3) * inv;
            float u1 = g1x * c1  - g1y * s1;
            float u2 = g2x * c2a - g2y * s2a;
            float u3 = g3x * c3a - g3y * s3a;
            q0[j] = (g0x + u1 + u2 + u3) * inv;
            q1[j] = (g0x - u1 + u2 - u3) * inv;
            float nc = c1 * cr - s1 * sr;
            float ns = s1 * cr + c1 * sr;
            c1 = nc; s1 = ns;
        }
        __builtin_nontemporal_store(r0, (vfloat4*)(orow0 + lane * 4));
        __builtin_nontemporal_store(r1, (vfloat4*)(orow0 + 256 + lane * 4));
        __builtin_nontemporal_store(q0, (vfloat4*)(orow1 + lane * 4));
        __builtin_nontemporal_store(q1, (vfloat4*)(orow1 + 256 + lane * 4));
    }
}

extern "C" void kernel_launch(void* const* d_in, const int* in_sizes, int n_in,
                              void* d_out, int out_size, void* d_ws, size_t ws_size,
                              hipStream_t stream) {
    const float* x  = (const float*)d_in[0];
    const float* w1 = (const float*)d_in[3];
    const float* w2 = (const float*)d_in[4];
    float* out = (float*)d_out;

    float* Yg = (float*)d_ws;                        // [8][16][8][64] = 256 KB
    unsigned int* done = (unsigned int*)(Yg + 65536);// 8 uints

    int maxb = 0;
    bool pipe_ok =
        (hipOccupancyMaxActiveBlocksPerMultiprocessor(&maxb, (const void*)k_pipe, 256, 0)
             == hipSuccess) && (maxb >= 8);

    if (pipe_ok) {
        hipMemsetAsync(done, 0, 8 * sizeof(unsigned int), stream);
        k_pipe<<<2048, 256, 0, stream>>>(x, w1, w2, Yg, done, out);
    } else {
        k_dft_t<<<1024, 256, 0, stream>>>(x, Yg);
        k_mix_eval<<<2048, 256, 0, stream>>>(Yg, w1, w2, out);
    }
}